// Round 14
// baseline (727.052 us; speedup 1.0000x reference)
//
#include <hip/hip_runtime.h>

// Problem constants: B=N=256, D=S=1024
// out = [ctx 256*1024 fp32 ; W 256*256*1024 fp32]

typedef _Float16 half8 __attribute__((ext_vector_type(8)));
typedef float floatx16 __attribute__((ext_vector_type(16)));

static __device__ __forceinline__ void split_f32(float x, _Float16& hi, _Float16& lo) {
    _Float16 h = (_Float16)x;
    hi = h;
    lo = (_Float16)(x - (float)h);
}

// ---------------------------------------------------------------------------
// Split-K small GEMM (R6, proven): C[M,N] += A[M,K-slice] @ B, fp32 atomicAdd
// epilogue. fp32 in, hi/lo fp16 split on BOTH operands (3 MFMAs).
// Tile 64x64, 256 threads, BK=32.
// ---------------------------------------------------------------------------
template <bool BT>
__global__ __launch_bounds__(256, 2) void gemm_splitk(
    const float* __restrict__ Ag, const float* __restrict__ Bg,
    float* __restrict__ Cf, int Kdim, int Ndim, int KC)
{
    __shared__ __align__(16) _Float16 AsHi[4 * 64 * 8];
    __shared__ __align__(16) _Float16 AsLo[4 * 64 * 8];
    __shared__ __align__(16) _Float16 BsHi[4 * 64 * 8];
    __shared__ __align__(16) _Float16 BsLo[4 * 64 * 8];

    const int tid  = threadIdx.x;
    const int lane = tid & 63;
    const int wave = tid >> 6;
    const int wy = wave >> 1, wx = wave & 1;
    const int l31 = lane & 31, l5 = lane >> 5;
    const int m0 = blockIdx.y * 64, n0 = blockIdx.x * 64;
    const int kt0 = (blockIdx.z * KC) >> 5;

    floatx16 acc;
#pragma unroll
    for (int j = 0; j < 16; ++j) acc[j] = 0.0f;

    const int sA_m  = tid >> 2;
    const int sA_kg = tid & 3;
    const int sB_n  = tid & 63;
    const int sB_kg = tid >> 6;

    const int nkt = KC / 32;
#pragma unroll 1
    for (int kt2 = 0; kt2 < nkt; ++kt2) {
        const int kt = kt0 + kt2;
        __syncthreads();
        {
            const float* src = Ag + (size_t)(m0 + sA_m) * Kdim + kt * 32 + sA_kg * 8;
            half8 hi, lo;
#pragma unroll
            for (int j = 0; j < 8; ++j) {
                _Float16 h, l;
                split_f32(src[j], h, l);
                hi[j] = h; lo[j] = l;
            }
            *(half8*)&AsHi[(sA_kg * 64 + sA_m) * 8] = hi;
            *(half8*)&AsLo[(sA_kg * 64 + sA_m) * 8] = lo;
        }
        if constexpr (BT) {
            const float* src = Bg + (size_t)(n0 + sA_m) * Kdim + kt * 32 + sA_kg * 8;
            half8 hi, lo;
#pragma unroll
            for (int j = 0; j < 8; ++j) {
                _Float16 h, l;
                split_f32(src[j], h, l);
                hi[j] = h; lo[j] = l;
            }
            *(half8*)&BsHi[(sA_kg * 64 + sA_m) * 8] = hi;
            *(half8*)&BsLo[(sA_kg * 64 + sA_m) * 8] = lo;
        } else {
            const float* src = Bg + (size_t)(kt * 32 + sB_kg * 8) * Ndim + n0 + sB_n;
            half8 hi, lo;
#pragma unroll
            for (int j = 0; j < 8; ++j) {
                _Float16 h, l;
                split_f32(src[(size_t)j * Ndim], h, l);
                hi[j] = h; lo[j] = l;
            }
            *(half8*)&BsHi[(sB_kg * 64 + sB_n) * 8] = hi;
            *(half8*)&BsLo[(sB_kg * 64 + sB_n) * 8] = lo;
        }
        __syncthreads();
#pragma unroll
        for (int ks = 0; ks < 2; ++ks) {
            const int kg = ks * 2 + l5;
            const half8 ah = *(half8*)&AsHi[(kg * 64 + wy * 32 + l31) * 8];
            const half8 al = *(half8*)&AsLo[(kg * 64 + wy * 32 + l31) * 8];
            const half8 bh = *(half8*)&BsHi[(kg * 64 + wx * 32 + l31) * 8];
            const half8 bl = *(half8*)&BsLo[(kg * 64 + wx * 32 + l31) * 8];
            acc = __builtin_amdgcn_mfma_f32_32x32x16_f16(ah, bh, acc, 0, 0, 0);
            acc = __builtin_amdgcn_mfma_f32_32x32x16_f16(ah, bl, acc, 0, 0, 0);
            acc = __builtin_amdgcn_mfma_f32_32x32x16_f16(al, bh, acc, 0, 0, 0);
        }
    }

    // C/D layout (verified): col = lane&31, row = (reg&3) + 8*(reg>>2) + 4*(lane>>5)
#pragma unroll
    for (int reg = 0; reg < 16; ++reg) {
        const int row = m0 + wy * 32 + (reg & 3) + 8 * (reg >> 2) + 4 * l5;
        const int col = n0 + wx * 32 + l31;
        atomicAdd(&Cf[(size_t)row * Ndim + col], acc[reg]);
    }
}

// 5-bit XOR swizzle for the persistent FV16 LDS tile Bs[d][n] (row = 512 B):
// flips 16B-slot index (bits 4..8) with d&31 (bits 9..13). Bijective within
// each d-row; applied identically on write, fragment-read, and ctx-read.
// Patterns: stage-write 2-way, frag-read (d per lane) distinct-slot,
// ctx-read distinct-slot.
static __device__ __forceinline__ int swz5(int byte_off) {
    return byte_off ^ (((byte_off >> 9) & 31) << 4);
}

// ---------------------------------------------------------------------------
// Two-pass d-slice fused attention (R14).
// Block = (i, d-slice of 256): owns ALL 256 b-rows x 256 d-cols ->
// each FV element staged by EXACTLY ONE block (multicast 1x, was 4x).
// FV16 slice (256n x 256d = 128 KB) lives in LDS PERSISTENTLY (160 KB/CU):
// staged once per chunk into its unique region (one barrier/chunk, no
// double buffer), used as MFMA B-operand, and re-read by the ctx epilogue
// from LDS (zero second global FV read).
// PASS 1: logits -> per-row partial (max m_p, sum S_p) -> stats arrays.
// PASS 2: recompute logits (MFMA is cheap: ~17 us/pass), combine stats
// exactly (m = max m_p; S = sum S_p*exp(m_p-m)), write W, accumulate ctx.
// A-operand: M fp32 rows read per-fragment from global (256 KB, L2-hot),
// in-register hi/lo split (2 MFMAs per tile, proven accuracy).
// 512 threads = 8 waves: wy = wave>>1 (64 b-rows), wx = wave&1 (128 d).
// acc[8] = 2 b-tiles x 4 d-tiles of 32x32.
// ---------------------------------------------------------------------------
template <int PASS>
__global__ __launch_bounds__(512, 1) void pass_k(
    const float* __restrict__ FV, const float* __restrict__ Mf,
    float* __restrict__ Sm, float* __restrict__ Ss,
    float* __restrict__ ctx, float* __restrict__ Wout)
{
    __shared__ __align__(16) _Float16 Bs[256 * 256];  // [d][n] swizzled, 128 KB
    __shared__ __align__(16) float redm[256 * 2];
    __shared__ __align__(16) float reds[256 * 2];

    const int tid  = threadIdx.x;
    const int lane = tid & 63;
    const int wave = tid >> 6;      // 0..7
    const int wy   = wave >> 1;     // 0..3: b-quarter (64 rows)
    const int wx   = wave & 1;      // 0..1: d-half (128 cols)
    const int l31 = lane & 31, l5 = lane >> 5;

    const int i  = blockIdx.x >> 2;   // 0..255
    const int ds = blockIdx.x & 3;    // 0..3

    const float* __restrict__ FVi = FV + (size_t)i * 262144 + ds * 256;

    floatx16 acc[8];
#pragma unroll
    for (int t = 0; t < 8; ++t)
#pragma unroll
        for (int j = 0; j < 16; ++j) acc[t][j] = 0.0f;

    // staging: thread owns d = tid&255, n-octet snh = tid>>8 within each chunk
    const int sd  = tid & 255;
    const int snh = tid >> 8;

    // A-fragment row pointers (Mf fp32, L2-hot): rows wy*64 + {0,32} + l31
    const float* __restrict__ Ar0 = Mf + (size_t)(wy * 64 + l31) * 256 + l5 * 8;
    const float* __restrict__ Ar1 = Mf + (size_t)(wy * 64 + 32 + l31) * 256 + l5 * 8;

    // ---- prefetch chunk 0 staging (8 lane-coalesced scalar loads) ----
    float pv[8];
#pragma unroll
    for (int r = 0; r < 8; ++r)
        pv[r] = FVi[(size_t)(snh * 8 + r) * 1024 + sd];

#pragma unroll 1
    for (int kt = 0; kt < 16; ++kt) {
        // write staged chunk kt into its unique persistent region (no WAR)
        {
            half8 h;
#pragma unroll
            for (int r = 0; r < 8; ++r) h[r] = (_Float16)pv[r];
            const int byte_off = sd * 512 + (kt * 16 + snh * 8) * 2;
            *(half8*)((char*)Bs + swz5(byte_off)) = h;
        }
        __syncthreads();
        // prefetch next chunk (overlaps with compute below)
        if (kt + 1 < 16) {
#pragma unroll
            for (int r = 0; r < 8; ++r)
                pv[r] = FVi[(size_t)((kt + 1) * 16 + snh * 8 + r) * 1024 + sd];
        }
        // A-fragments: fp32 -> hi/lo in-register
        half8 ah0, al0, ah1, al1;
        {
            const float4 x0 = *(const float4*)(Ar0 + kt * 16);
            const float4 x1 = *(const float4*)(Ar0 + kt * 16 + 4);
            const float4 y0 = *(const float4*)(Ar1 + kt * 16);
            const float4 y1 = *(const float4*)(Ar1 + kt * 16 + 4);
#pragma unroll
            for (int j = 0; j < 4; ++j) {
                _Float16 h, l;
                split_f32((&x0.x)[j], h, l); ah0[j] = h;     al0[j] = l;
                split_f32((&x1.x)[j], h, l); ah0[4 + j] = h; al0[4 + j] = l;
                split_f32((&y0.x)[j], h, l); ah1[j] = h;     al1[j] = l;
                split_f32((&y1.x)[j], h, l); ah1[4 + j] = h; al1[4 + j] = l;
            }
        }
        // B-fragments from persistent LDS + MFMA (4 d-tiles x 2 b-tiles)
#pragma unroll
        for (int dt = 0; dt < 4; ++dt) {
            const int byte_off = (wx * 128 + dt * 32 + l31) * 512 + (kt * 16 + l5 * 8) * 2;
            const half8 b = *(const half8*)((const char*)Bs + swz5(byte_off));
            acc[dt]     = __builtin_amdgcn_mfma_f32_32x32x16_f16(ah0, b, acc[dt], 0, 0, 0);
            acc[dt]     = __builtin_amdgcn_mfma_f32_32x32x16_f16(al0, b, acc[dt], 0, 0, 0);
            acc[4 + dt] = __builtin_amdgcn_mfma_f32_32x32x16_f16(ah1, b, acc[4 + dt], 0, 0, 0);
            acc[4 + dt] = __builtin_amdgcn_mfma_f32_32x32x16_f16(al1, b, acc[4 + dt], 0, 0, 0);
        }
    }

    // acc[mt*4+dt][reg]: row(b) = wy*64 + mt*32 + (reg&3)+8*(reg>>2)+4*l5,
    //                    col(d_local) = wx*128 + dt*32 + l31
    if constexpr (PASS == 1) {
        // ---- per-row partial max over this block's 256 d ----
#pragma unroll
        for (int mt = 0; mt < 2; ++mt)
#pragma unroll
            for (int reg = 0; reg < 16; ++reg) {
                float v = fmaxf(fmaxf(acc[mt * 4 + 0][reg], acc[mt * 4 + 1][reg]),
                                fmaxf(acc[mt * 4 + 2][reg], acc[mt * 4 + 3][reg]));
#pragma unroll
                for (int off = 1; off < 32; off <<= 1) v = fmaxf(v, __shfl_xor(v, off));
                if (l31 == 0) {
                    const int row = wy * 64 + mt * 32 + (reg & 3) + 8 * (reg >> 2) + 4 * l5;
                    redm[row * 2 + wx] = v;
                }
            }
        __syncthreads();
        // ---- partial exp-sum with the block-combined partial max ----
#pragma unroll
        for (int mt = 0; mt < 2; ++mt)
#pragma unroll
            for (int reg = 0; reg < 16; ++reg) {
                const int row = wy * 64 + mt * 32 + (reg & 3) + 8 * (reg >> 2) + 4 * l5;
                const float m = fmaxf(redm[row * 2], redm[row * 2 + 1]);
                float s = 0.0f;
#pragma unroll
                for (int dt = 0; dt < 4; ++dt) s += __expf(acc[mt * 4 + dt][reg] - m);
#pragma unroll
                for (int off = 1; off < 32; off <<= 1) s += __shfl_xor(s, off);
                if (l31 == 0) reds[row * 2 + wx] = s;
            }
        __syncthreads();
        if (tid < 256) {
            const int b = tid;
            const float m = fmaxf(redm[b * 2], redm[b * 2 + 1]);
            const float s = reds[b * 2] + reds[b * 2 + 1];
            const int sidx = (i * 4 + ds) * 256 + b;
            Sm[sidx] = m;
            Ss[sidx] = s;
        }
    } else {
        // ---- combine the 4 slice-partials into exact global (m, 1/S) ----
        if (tid < 256) {
            const int b = tid;
            float pm[4], ps[4];
            float m = -3.0e38f;
#pragma unroll
            for (int p = 0; p < 4; ++p) {
                pm[p] = Sm[(i * 4 + p) * 256 + b];
                ps[p] = Ss[(i * 4 + p) * 256 + b];
                m = fmaxf(m, pm[p]);
            }
            float S = 0.0f;
#pragma unroll
            for (int p = 0; p < 4; ++p) S += ps[p] * __expf(pm[p] - m);
            redm[b] = m;
            reds[b] = 1.0f / S;
        }
        __syncthreads();
        // ---- emit W + accumulate ctx (FV16 from persistent LDS) ----
#pragma unroll
        for (int dt = 0; dt < 4; ++dt) {
            const int dloc  = wx * 128 + dt * 32 + l31;
            const int dbyte = dloc * 512;
            float csum = 0.0f;
#pragma unroll
            for (int mt = 0; mt < 2; ++mt)
#pragma unroll
                for (int no = 0; no < 4; ++no) {
                    const half8 f = *(const half8*)((const char*)Bs +
                        swz5(dbyte + (wy * 64 + mt * 32 + no * 8) * 2));
#pragma unroll
                    for (int rq = 0; rq < 4; ++rq) {
                        const int reg = no * 4 + rq;
                        const int row = wy * 64 + mt * 32 + rq + 8 * no + 4 * l5;
                        const float wv = __expf(acc[mt * 4 + dt][reg] - redm[row]) * reds[row];
                        Wout[((size_t)(i * 256 + row)) * 1024 + ds * 256 + dloc] = wv;
                        csum += wv * (float)f[rq + 4 * l5];
                    }
                }
            const float v = csum + __shfl_xor(csum, 32);
            if (l5 == 0)
                atomicAdd(&ctx[(size_t)i * 1024 + ds * 256 + dloc], v);
        }
    }
}

// ---------------------------------------------------------------------------
extern "C" void kernel_launch(void* const* d_in, const int* in_sizes, int n_in,
                              void* d_out, int out_size, void* d_ws, size_t ws_size,
                              hipStream_t stream)
{
    const float* FV    = (const float*)d_in[0];  // [256,256,1024]
    const float* state = (const float*)d_in[1];  // [256,1024]
    const float* Q     = (const float*)d_in[2];  // [1024,1024]
    const float* Km    = (const float*)d_in[3];  // [1024,256]

    float* out = (float*)d_out;
    float* ctx = out;                 // [256,1024]
    float* W   = out + 256 * 1024;    // [256,256,1024]

    char* ws = (char*)d_ws;
    float* A1 = (float*)ws;                             // [256,1024] fp32, 1 MB
    float* Mf = (float*)(ws + (1 << 20));               // [256,256]  fp32, 256 KB
    float* Sm = (float*)(ws + (1 << 20) + (1 << 18));   // [1024,256] fp32, 1 MB
    float* Ss = (float*)(ws + (2 << 20) + (1 << 18));   // [1024,256] fp32, 1 MB

    // split-K accumulators (A1, Mf) + ctx atomics -> zero (stats are
    // written before read, no memset needed)
    (void)hipMemsetAsync(ws, 0, (1 << 20) + (1 << 18), stream);
    (void)hipMemsetAsync(ctx, 0, 256 * 1024 * sizeof(float), stream);

    // A1 = state @ Q^T   (B stored [N,K]: Q[s,t], contract t), split-K x8
    gemm_splitk<true><<<dim3(16, 4, 8), 256, 0, stream>>>(
        state, Q, A1, 1024, 1024, 128);

    // M = A1 @ K  (B stored [K,N]), split-K x16
    gemm_splitk<false><<<dim3(4, 4, 16), 256, 0, stream>>>(
        A1, Km, Mf, 1024, 256, 64);

    // pass 1: logits -> per-(i,b,slice) partial (max, expsum)
    pass_k<1><<<dim3(1024), 512, 0, stream>>>(FV, Mf, Sm, Ss, ctx, W);

    // pass 2: recompute logits, exact softmax combine, emit W + ctx
    pass_k<2><<<dim3(1024), 512, 0, stream>>>(FV, Mf, Sm, Ss, ctx, W);
}

// Round 15
// 696.653 us; speedup vs baseline: 1.0436x; 1.0436x over previous
//
#include <hip/hip_runtime.h>

// Problem constants: B=N=256, D=S=1024
// out = [ctx 256*1024 fp32 ; W 256*256*1024 fp32]

typedef _Float16 half8 __attribute__((ext_vector_type(8)));
typedef float floatx16 __attribute__((ext_vector_type(16)));

static __device__ __forceinline__ void split_f32(float x, _Float16& hi, _Float16& lo) {
    _Float16 h = (_Float16)x;
    hi = h;
    lo = (_Float16)(x - (float)h);
}

// ---------------------------------------------------------------------------
// Split-K small GEMM (R6, proven): C[M,N] += A[M,K-slice] @ B, fp32 atomicAdd
// epilogue. fp32 in, hi/lo fp16 split on BOTH operands (3 MFMAs).
// Tile 64x64, 256 threads, BK=32.
// ---------------------------------------------------------------------------
template <bool BT>
__global__ __launch_bounds__(256, 2) void gemm_splitk(
    const float* __restrict__ Ag, const float* __restrict__ Bg,
    float* __restrict__ Cf, int Kdim, int Ndim, int KC)
{
    __shared__ __align__(16) _Float16 AsHi[4 * 64 * 8];
    __shared__ __align__(16) _Float16 AsLo[4 * 64 * 8];
    __shared__ __align__(16) _Float16 BsHi[4 * 64 * 8];
    __shared__ __align__(16) _Float16 BsLo[4 * 64 * 8];

    const int tid  = threadIdx.x;
    const int lane = tid & 63;
    const int wave = tid >> 6;
    const int wy = wave >> 1, wx = wave & 1;
    const int l31 = lane & 31, l5 = lane >> 5;
    const int m0 = blockIdx.y * 64, n0 = blockIdx.x * 64;
    const int kt0 = (blockIdx.z * KC) >> 5;

    floatx16 acc;
#pragma unroll
    for (int j = 0; j < 16; ++j) acc[j] = 0.0f;

    const int sA_m  = tid >> 2;
    const int sA_kg = tid & 3;
    const int sB_n  = tid & 63;
    const int sB_kg = tid >> 6;

    const int nkt = KC / 32;
#pragma unroll 1
    for (int kt2 = 0; kt2 < nkt; ++kt2) {
        const int kt = kt0 + kt2;
        __syncthreads();
        {
            const float* src = Ag + (size_t)(m0 + sA_m) * Kdim + kt * 32 + sA_kg * 8;
            half8 hi, lo;
#pragma unroll
            for (int j = 0; j < 8; ++j) {
                _Float16 h, l;
                split_f32(src[j], h, l);
                hi[j] = h; lo[j] = l;
            }
            *(half8*)&AsHi[(sA_kg * 64 + sA_m) * 8] = hi;
            *(half8*)&AsLo[(sA_kg * 64 + sA_m) * 8] = lo;
        }
        if constexpr (BT) {
            const float* src = Bg + (size_t)(n0 + sA_m) * Kdim + kt * 32 + sA_kg * 8;
            half8 hi, lo;
#pragma unroll
            for (int j = 0; j < 8; ++j) {
                _Float16 h, l;
                split_f32(src[j], h, l);
                hi[j] = h; lo[j] = l;
            }
            *(half8*)&BsHi[(sA_kg * 64 + sA_m) * 8] = hi;
            *(half8*)&BsLo[(sA_kg * 64 + sA_m) * 8] = lo;
        } else {
            const float* src = Bg + (size_t)(kt * 32 + sB_kg * 8) * Ndim + n0 + sB_n;
            half8 hi, lo;
#pragma unroll
            for (int j = 0; j < 8; ++j) {
                _Float16 h, l;
                split_f32(src[(size_t)j * Ndim], h, l);
                hi[j] = h; lo[j] = l;
            }
            *(half8*)&BsHi[(sB_kg * 64 + sB_n) * 8] = hi;
            *(half8*)&BsLo[(sB_kg * 64 + sB_n) * 8] = lo;
        }
        __syncthreads();
#pragma unroll
        for (int ks = 0; ks < 2; ++ks) {
            const int kg = ks * 2 + l5;
            const half8 ah = *(half8*)&AsHi[(kg * 64 + wy * 32 + l31) * 8];
            const half8 al = *(half8*)&AsLo[(kg * 64 + wy * 32 + l31) * 8];
            const half8 bh = *(half8*)&BsHi[(kg * 64 + wx * 32 + l31) * 8];
            const half8 bl = *(half8*)&BsLo[(kg * 64 + wx * 32 + l31) * 8];
            acc = __builtin_amdgcn_mfma_f32_32x32x16_f16(ah, bh, acc, 0, 0, 0);
            acc = __builtin_amdgcn_mfma_f32_32x32x16_f16(ah, bl, acc, 0, 0, 0);
            acc = __builtin_amdgcn_mfma_f32_32x32x16_f16(al, bh, acc, 0, 0, 0);
        }
    }

    // C/D layout (verified): col = lane&31, row = (reg&3) + 8*(reg>>2) + 4*(lane>>5)
#pragma unroll
    for (int reg = 0; reg < 16; ++reg) {
        const int row = m0 + wy * 32 + (reg & 3) + 8 * (reg >> 2) + 4 * l5;
        const int col = n0 + wx * 32 + l31;
        atomicAdd(&Cf[(size_t)row * Ndim + col], acc[reg]);
    }
}

// Bank swizzle (proven R9): XOR bits[6:4] with bits[9:7]. Involution;
// applied identically on store and read, so placement is self-consistent.
static __device__ __forceinline__ int bs_swz(int byte_off) {
    return byte_off ^ (((byte_off >> 7) & 7) << 4);
}

// ---------------------------------------------------------------------------
// Fused R15 = R9 (best, 255 us; stagger/nt reverted as measured-negative)
// + PERSISTENT-LDS EPILOGUE for the lower 32 rows.
// Delivery model (confirmed R13: fused time ~ delivered VMEM bytes / 6.3TB/s):
// R9 delivers 4x268 multicast + 268 epilogue re-read + 268 W = 1.6 GB ->
// floor 254, measured 255. The epilogue re-read of rows [bt*64, bt*64+32)
// was ALREADY staged at chunks kt = {4bt, 4bt+1}: store the same half8 into
// a persistent 64 KB region P (granule layout identical to Bs) and have
// wy=0 waves read epilogue fv from P (fp16, R5/R13-proven accurate);
// wy=1 keeps the global fp32 read. Saves 134 MB delivered (~21 us).
// LDS total 102 KB (<160), occupancy unchanged (reg-bound at 8 waves).
// ---------------------------------------------------------------------------
__global__ __launch_bounds__(512, 2) void fused_attn(
    const float* __restrict__ FV, const float* __restrict__ Mf,
    float* __restrict__ ctx, float* __restrict__ Wout)
{
    __shared__ __align__(16) _Float16 AsHi[2 * 64 * 8];
    __shared__ __align__(16) _Float16 AsLo[2 * 64 * 8];
    __shared__ __align__(16) _Float16 Bs[2 * 1024 * 8];
    __shared__ __align__(16) _Float16 P[4 * 1024 * 8];   // rows bt*64..+32, 64 KB
    __shared__ __align__(16) float red1[64 * 4];
    __shared__ __align__(16) float red2[64 * 4];

    const int tid  = threadIdx.x;
    const int lane = tid & 63;
    const int wave = tid >> 6;
    const int wx = wave & 3;   // d-slice (256 cols)
    const int wy = wave >> 2;  // m-half (32 rows)
    const int l31 = lane & 31, l5 = lane >> 5;

    // XCD-aware swizzle: all 4 bt of an i share one XCD.
    const int w   = blockIdx.x;   // 0..1023
    const int xcd = w & 7;
    const int k   = w >> 3;       // 0..127
    const int i   = (xcd << 5) + (k >> 2);  // 0..255
    const int bt  = k & 3;                  // 0..3

    const float* __restrict__ FVi = FV + (size_t)i * 256 * 1024;

    floatx16 acc[8];
#pragma unroll
    for (int nt = 0; nt < 8; ++nt)
#pragma unroll
        for (int j = 0; j < 16; ++j) acc[nt][j] = 0.0f;

    const int am = tid >> 1, akg = tid & 1;  // A staging (tid < 128)

    // B staging mapping (R9): thread owns n-subgroup n8 = tid>>8 (8 rows) and
    // cols [c0, c0+4), c0 = (tid&255)*4. 8x float4 per chunk.
    const int n8 = tid >> 8;
    const int c0 = (tid & 255) * 4;

    // ---- prefetch chunk 0 into registers ----
    float4 pv4[8];
    float4 pa0, pa1;
    {
        const float* src = FVi + (size_t)(n8 * 8) * 1024 + c0;
#pragma unroll
        for (int r = 0; r < 8; ++r) pv4[r] = *(const float4*)(src + (size_t)r * 1024);
    }
    if (tid < 128) {
        const float* ap = Mf + (size_t)(bt * 64 + am) * 256 + akg * 8;
        pa0 = *(const float4*)(ap);
        pa1 = *(const float4*)(ap + 4);
    }

#pragma unroll 1
    for (int kt = 0; kt < 16; ++kt) {
        __syncthreads();  // drains prefetch (issued a full compute-phase ago)
        // ---- store staged chunk to LDS (fp32 M split to hi/lo here) ----
        if (tid < 128) {
            half8 hi, lo;
#pragma unroll
            for (int j = 0; j < 4; ++j) {
                _Float16 h, l;
                split_f32((&pa0.x)[j], h, l);
                hi[j] = h; lo[j] = l;
            }
#pragma unroll
            for (int j = 0; j < 4; ++j) {
                _Float16 h, l;
                split_f32((&pa1.x)[j], h, l);
                hi[4 + j] = h; lo[4 + j] = l;
            }
            *(half8*)&AsHi[(akg * 64 + am) * 8] = hi;
            *(half8*)&AsLo[(akg * 64 + am) * 8] = lo;
        }
        // B: in-register 8x4 transpose -> 4 half8 stores (swizzled banks).
        // If this chunk's rows fall in [bt*64, bt*64+32), also retain the
        // same half8 in the persistent region P (rows kt*16+n8*8 .. +8).
        const bool toP = ((kt >> 2) == bt) && ((kt & 3) < 2);
        const int  q   = (kt & 1) * 2 + n8;   // granule-row 0..3 within P
#pragma unroll
        for (int j = 0; j < 4; ++j) {
            half8 h;
#pragma unroll
            for (int r = 0; r < 8; ++r) h[r] = (_Float16)((&pv4[r].x)[j]);
            const int byte_off = (n8 * 1024 + c0 + j) * 16;
            *(half8*)((char*)Bs + bs_swz(byte_off)) = h;
            if (toP)
                *(half8*)((char*)P + bs_swz((q * 1024 + c0 + j) * 16)) = h;
        }
        __syncthreads();
        // ---- prefetch next chunk (overlaps with compute below) ----
        if (kt + 1 < 16) {
            const float* src = FVi + (size_t)((kt + 1) * 16 + n8 * 8) * 1024 + c0;
#pragma unroll
            for (int r = 0; r < 8; ++r) pv4[r] = *(const float4*)(src + (size_t)r * 1024);
            if (tid < 128) {
                const float* ap = Mf + (size_t)(bt * 64 + am) * 256 + (kt + 1) * 16 + akg * 8;
                pa0 = *(const float4*)(ap);
                pa1 = *(const float4*)(ap + 4);
            }
        }
        // ---- compute: 8 n-tiles x (hi,lo) MFMA ----
        const half8 ah = *(half8*)&AsHi[(l5 * 64 + wy * 32 + l31) * 8];
        const half8 al = *(half8*)&AsLo[(l5 * 64 + wy * 32 + l31) * 8];
#pragma unroll
        for (int nt = 0; nt < 8; ++nt) {
            const int byte_off = (l5 * 1024 + wx * 256 + nt * 32 + l31) * 16;
            const half8 b = *(const half8*)((const char*)Bs + bs_swz(byte_off));
            acc[nt] = __builtin_amdgcn_mfma_f32_32x32x16_f16(ah, b, acc[nt], 0, 0, 0);
            acc[nt] = __builtin_amdgcn_mfma_f32_32x32x16_f16(al, b, acc[nt], 0, 0, 0);
        }
    }

    // ---- softmax over d (rows span 4 wx waves) ----
    // lane holds: col = wx*256 + nt*32 + l31 ; row = wy*32 + (reg&3)+8*(reg>>2)+4*l5
    float st[16];
#pragma unroll
    for (int reg = 0; reg < 16; ++reg) {
        float v = acc[0][reg];
#pragma unroll
        for (int nt = 1; nt < 8; ++nt) v = fmaxf(v, acc[nt][reg]);
#pragma unroll
        for (int off = 1; off < 32; off <<= 1) v = fmaxf(v, __shfl_xor(v, off));
        st[reg] = v;
    }
    if (l31 == 0) {
#pragma unroll
        for (int reg = 0; reg < 16; ++reg) {
            const int row = wy * 32 + (reg & 3) + 8 * (reg >> 2) + 4 * l5;
            red1[row * 4 + wx] = st[reg];
        }
    }
    __syncthreads();
    float rmax[16];
#pragma unroll
    for (int reg = 0; reg < 16; ++reg) {
        const int row = wy * 32 + (reg & 3) + 8 * (reg >> 2) + 4 * l5;
        const float4 m4 = *(const float4*)&red1[row * 4];
        rmax[reg] = fmaxf(fmaxf(m4.x, m4.y), fmaxf(m4.z, m4.w));
    }
#pragma unroll
    for (int reg = 0; reg < 16; ++reg) {
        float s = 0.0f;
#pragma unroll
        for (int nt = 0; nt < 8; ++nt) {
            const float p = __expf(acc[nt][reg] - rmax[reg]);
            acc[nt][reg] = p;
            s += p;
        }
#pragma unroll
        for (int off = 1; off < 32; off <<= 1) s += __shfl_xor(s, off);
        st[reg] = s;
    }
    if (l31 == 0) {
#pragma unroll
        for (int reg = 0; reg < 16; ++reg) {
            const int row = wy * 32 + (reg & 3) + 8 * (reg >> 2) + 4 * l5;
            red2[row * 4 + wx] = st[reg];
        }
    }
    __syncthreads();
    float inv[16];
#pragma unroll
    for (int reg = 0; reg < 16; ++reg) {
        const int row = wy * 32 + (reg & 3) + 8 * (reg >> 2) + 4 * l5;
        const float4 s4 = *(const float4*)&red2[row * 4];
        inv[reg] = 1.0f / (s4.x + s4.y + s4.z + s4.w);
    }

    // ---- write W, accumulate context ----
    // wy==0 rows (bt*64 .. +32): fv from persistent LDS P (fp16).
    // wy==1 rows (bt*64+32 .. +64): fv from global fp32 (as R9).
    float csum[8];
#pragma unroll
    for (int nt = 0; nt < 8; ++nt) csum[nt] = 0.0f;

    const int rowbase = bt * 64 + wy * 32;
#pragma unroll
    for (int nt = 0; nt < 8; ++nt) {
        const int col = wx * 256 + nt * 32 + l31;
        half8 pf[4];
        if (wy == 0) {
#pragma unroll
            for (int no = 0; no < 4; ++no)
                pf[no] = *(const half8*)((const char*)P + bs_swz((no * 1024 + col) * 16));
        }
#pragma unroll
        for (int reg = 0; reg < 16; ++reg) {
            const int row = (reg & 3) + 8 * (reg >> 2) + 4 * l5;
            const float wv = acc[nt][reg] * inv[reg];
            Wout[((size_t)(i * 256 + rowbase + row)) * 1024 + col] = wv;
            float fv;
            if (wy == 0) fv = (float)pf[reg >> 2][(reg & 3) + 4 * l5];
            else         fv = FVi[(size_t)(rowbase + row) * 1024 + col];
            csum[nt] += wv * fv;
        }
    }
#pragma unroll
    for (int nt = 0; nt < 8; ++nt) {
        const float v = csum[nt] + __shfl_xor(csum[nt], 32);
        if (l5 == 0)
            atomicAdd(&ctx[(size_t)i * 1024 + wx * 256 + nt * 32 + l31], v);
    }
}

// ---------------------------------------------------------------------------
extern "C" void kernel_launch(void* const* d_in, const int* in_sizes, int n_in,
                              void* d_out, int out_size, void* d_ws, size_t ws_size,
                              hipStream_t stream)
{
    const float* FV    = (const float*)d_in[0];  // [256,256,1024]
    const float* state = (const float*)d_in[1];  // [256,1024]
    const float* Q     = (const float*)d_in[2];  // [1024,1024]
    const float* Km    = (const float*)d_in[3];  // [1024,256]

    float* out = (float*)d_out;
    float* ctx = out;                 // [256,1024]
    float* W   = out + 256 * 1024;    // [256,256,1024]

    char* ws = (char*)d_ws;
    float* A1 = (float*)ws;               // [256,1024] fp32, 1 MB
    float* Mf = (float*)(ws + (1 << 20)); // [256,256]  fp32, 256 KB

    // split-K accumulators + ctx atomics -> zero them
    (void)hipMemsetAsync(ws, 0, (1 << 20) + (1 << 18), stream);
    (void)hipMemsetAsync(ctx, 0, 256 * 1024 * sizeof(float), stream);

    // A1 = state @ Q^T   (B stored [N,K]: Q[s,t], contract t), split-K x8
    gemm_splitk<true><<<dim3(16, 4, 8), 256, 0, stream>>>(
        state, Q, A1, 1024, 1024, 128);

    // M = A1 @ K  (B stored [K,N]), split-K x16
    gemm_splitk<false><<<dim3(4, 4, 16), 256, 0, stream>>>(
        A1, Km, Mf, 1024, 256, 64);

    // fused logits -> softmax -> W + ctx (R9 structure + LDS-persistent rows)
    fused_attn<<<dim3(1024), 512, 0, stream>>>(FV, Mf, ctx, W);
}

// Round 16
// 587.426 us; speedup vs baseline: 1.2377x; 1.1859x over previous
//
#include <hip/hip_runtime.h>

// Problem constants: B=N=256, D=S=1024
// out = [ctx 256*1024 fp32 ; W 256*256*1024 fp32]
//
// FINAL (R16 = R9 restored, session best):
//  - fused_attn measured 255.0 us = 99.5% of its delivery roofline:
//    delivered VMEM bytes = 4x268 MB multicast staging (register-file-forced:
//    softmax-over-d requires 4 blocks/i, each staging all of FV[i]) +
//    268 MB epilogue re-read + 268 MB W stores = 1.6 GB at the measured
//    6.3 TB/s delivery ceiling -> 254 us floor. [Model confirmed R13:
//    halving staged bytes via fp16 moved dur proportionally.]
//  - Structural alternatives all bought back their savings: fp16-copy
//    (R13: +122 us copy pass), two-pass d-slice (R14: 2x220 us),
//    LDS-persistent epilogue (R15: +116 us regression).
//  - Scheduling levers all delivery-neutral -> null: occupancy (R2/R4/R10),
//    barriers (R3), stagger (R12), nt-stores (R11).
//  - Split-K gemms (R6): fill the machine, ~55 us combined.
// ---------------------------------------------------------------------------

typedef _Float16 half8 __attribute__((ext_vector_type(8)));
typedef float floatx16 __attribute__((ext_vector_type(16)));

static __device__ __forceinline__ void split_f32(float x, _Float16& hi, _Float16& lo) {
    _Float16 h = (_Float16)x;
    hi = h;
    lo = (_Float16)(x - (float)h);
}

// ---------------------------------------------------------------------------
// Split-K small GEMM (R6, proven): C[M,N] += A[M,K-slice] @ B, fp32 atomicAdd
// epilogue. fp32 in, hi/lo fp16 split on BOTH operands (3 MFMAs).
// Tile 64x64, 256 threads, BK=32.
// ---------------------------------------------------------------------------
template <bool BT>
__global__ __launch_bounds__(256, 2) void gemm_splitk(
    const float* __restrict__ Ag, const float* __restrict__ Bg,
    float* __restrict__ Cf, int Kdim, int Ndim, int KC)
{
    __shared__ __align__(16) _Float16 AsHi[4 * 64 * 8];
    __shared__ __align__(16) _Float16 AsLo[4 * 64 * 8];
    __shared__ __align__(16) _Float16 BsHi[4 * 64 * 8];
    __shared__ __align__(16) _Float16 BsLo[4 * 64 * 8];

    const int tid  = threadIdx.x;
    const int lane = tid & 63;
    const int wave = tid >> 6;
    const int wy = wave >> 1, wx = wave & 1;
    const int l31 = lane & 31, l5 = lane >> 5;
    const int m0 = blockIdx.y * 64, n0 = blockIdx.x * 64;
    const int kt0 = (blockIdx.z * KC) >> 5;

    floatx16 acc;
#pragma unroll
    for (int j = 0; j < 16; ++j) acc[j] = 0.0f;

    const int sA_m  = tid >> 2;
    const int sA_kg = tid & 3;
    const int sB_n  = tid & 63;
    const int sB_kg = tid >> 6;

    const int nkt = KC / 32;
#pragma unroll 1
    for (int kt2 = 0; kt2 < nkt; ++kt2) {
        const int kt = kt0 + kt2;
        __syncthreads();
        {
            const float* src = Ag + (size_t)(m0 + sA_m) * Kdim + kt * 32 + sA_kg * 8;
            half8 hi, lo;
#pragma unroll
            for (int j = 0; j < 8; ++j) {
                _Float16 h, l;
                split_f32(src[j], h, l);
                hi[j] = h; lo[j] = l;
            }
            *(half8*)&AsHi[(sA_kg * 64 + sA_m) * 8] = hi;
            *(half8*)&AsLo[(sA_kg * 64 + sA_m) * 8] = lo;
        }
        if constexpr (BT) {
            const float* src = Bg + (size_t)(n0 + sA_m) * Kdim + kt * 32 + sA_kg * 8;
            half8 hi, lo;
#pragma unroll
            for (int j = 0; j < 8; ++j) {
                _Float16 h, l;
                split_f32(src[j], h, l);
                hi[j] = h; lo[j] = l;
            }
            *(half8*)&BsHi[(sA_kg * 64 + sA_m) * 8] = hi;
            *(half8*)&BsLo[(sA_kg * 64 + sA_m) * 8] = lo;
        } else {
            const float* src = Bg + (size_t)(kt * 32 + sB_kg * 8) * Ndim + n0 + sB_n;
            half8 hi, lo;
#pragma unroll
            for (int j = 0; j < 8; ++j) {
                _Float16 h, l;
                split_f32(src[(size_t)j * Ndim], h, l);
                hi[j] = h; lo[j] = l;
            }
            *(half8*)&BsHi[(sB_kg * 64 + sB_n) * 8] = hi;
            *(half8*)&BsLo[(sB_kg * 64 + sB_n) * 8] = lo;
        }
        __syncthreads();
#pragma unroll
        for (int ks = 0; ks < 2; ++ks) {
            const int kg = ks * 2 + l5;
            const half8 ah = *(half8*)&AsHi[(kg * 64 + wy * 32 + l31) * 8];
            const half8 al = *(half8*)&AsLo[(kg * 64 + wy * 32 + l31) * 8];
            const half8 bh = *(half8*)&BsHi[(kg * 64 + wx * 32 + l31) * 8];
            const half8 bl = *(half8*)&BsLo[(kg * 64 + wx * 32 + l31) * 8];
            acc = __builtin_amdgcn_mfma_f32_32x32x16_f16(ah, bh, acc, 0, 0, 0);
            acc = __builtin_amdgcn_mfma_f32_32x32x16_f16(ah, bl, acc, 0, 0, 0);
            acc = __builtin_amdgcn_mfma_f32_32x32x16_f16(al, bh, acc, 0, 0, 0);
        }
    }

    // C/D layout (verified): col = lane&31, row = (reg&3) + 8*(reg>>2) + 4*(lane>>5)
#pragma unroll
    for (int reg = 0; reg < 16; ++reg) {
        const int row = m0 + wy * 32 + (reg & 3) + 8 * (reg >> 2) + 4 * l5;
        const int col = n0 + wx * 32 + l31;
        atomicAdd(&Cf[(size_t)row * Ndim + col], acc[reg]);
    }
}

// Bank swizzle (proven R9): XOR bits[6:4] with bits[9:7]. Involution;
// applied identically on store and read, so placement is self-consistent.
static __device__ __forceinline__ int bs_swz(int byte_off) {
    return byte_off ^ (((byte_off >> 7) & 7) << 4);
}

// ---------------------------------------------------------------------------
// Fused (R9, session best: 255.0 us, 99.5% of delivery roofline):
// per (i, b-tile of 64): logits = M @ fp16(FV[i]) with in-register hi/lo
// split of fp32 M (2 MFMAs), row softmax over d=1024, write W, accumulate
// ctx[i,d] += W * FV[i,b,d].
// 512 threads = 8 waves (wy m-half, wx d-slice of 256); acc[8]; 1024 blocks;
// XCD-aware swizzle (4 lockstep siblings/i on one XCD -> FETCH ~= unique FV);
// float4 B-staging (wave = contiguous 1 KB per instruction) + in-register
// 8x4 transpose + swizzled b128 LDS stores; register prefetch one full
// compute-phase ahead.
// ---------------------------------------------------------------------------
__global__ __launch_bounds__(512, 2) void fused_attn(
    const float* __restrict__ FV, const float* __restrict__ Mf,
    float* __restrict__ ctx, float* __restrict__ Wout)
{
    __shared__ __align__(16) _Float16 AsHi[2 * 64 * 8];
    __shared__ __align__(16) _Float16 AsLo[2 * 64 * 8];
    __shared__ __align__(16) _Float16 Bs[2 * 1024 * 8];
    __shared__ __align__(16) float red1[64 * 4];
    __shared__ __align__(16) float red2[64 * 4];

    const int tid  = threadIdx.x;
    const int lane = tid & 63;
    const int wave = tid >> 6;
    const int wx = wave & 3;   // d-slice (256 cols)
    const int wy = wave >> 2;  // m-half (32 rows)
    const int l31 = lane & 31, l5 = lane >> 5;

    // XCD-aware swizzle: all 4 bt of an i share one XCD.
    const int w   = blockIdx.x;   // 0..1023
    const int xcd = w & 7;
    const int k   = w >> 3;       // 0..127
    const int i   = (xcd << 5) + (k >> 2);  // 0..255
    const int bt  = k & 3;                  // 0..3

    const float* __restrict__ FVi = FV + (size_t)i * 256 * 1024;

    floatx16 acc[8];
#pragma unroll
    for (int nt = 0; nt < 8; ++nt)
#pragma unroll
        for (int j = 0; j < 16; ++j) acc[nt][j] = 0.0f;

    const int am = tid >> 1, akg = tid & 1;  // A staging (tid < 128)

    // B staging mapping: thread owns n-subgroup n8 = tid>>8 (8 rows) and
    // cols [c0, c0+4), c0 = (tid&255)*4. 8x float4 per chunk.
    const int n8 = tid >> 8;
    const int c0 = (tid & 255) * 4;

    // ---- prefetch chunk 0 into registers ----
    float4 pv4[8];
    float4 pa0, pa1;
    {
        const float* src = FVi + (size_t)(n8 * 8) * 1024 + c0;
#pragma unroll
        for (int r = 0; r < 8; ++r) pv4[r] = *(const float4*)(src + (size_t)r * 1024);
    }
    if (tid < 128) {
        const float* ap = Mf + (size_t)(bt * 64 + am) * 256 + akg * 8;
        pa0 = *(const float4*)(ap);
        pa1 = *(const float4*)(ap + 4);
    }

#pragma unroll 1
    for (int kt = 0; kt < 16; ++kt) {
        __syncthreads();  // drains prefetch (issued a full compute-phase ago)
        // ---- store staged chunk to LDS (fp32 M split to hi/lo here) ----
        if (tid < 128) {
            half8 hi, lo;
#pragma unroll
            for (int j = 0; j < 4; ++j) {
                _Float16 h, l;
                split_f32((&pa0.x)[j], h, l);
                hi[j] = h; lo[j] = l;
            }
#pragma unroll
            for (int j = 0; j < 4; ++j) {
                _Float16 h, l;
                split_f32((&pa1.x)[j], h, l);
                hi[4 + j] = h; lo[4 + j] = l;
            }
            *(half8*)&AsHi[(akg * 64 + am) * 8] = hi;
            *(half8*)&AsLo[(akg * 64 + am) * 8] = lo;
        }
        // B: in-register 8x4 transpose -> 4 half8 stores (swizzled banks)
#pragma unroll
        for (int j = 0; j < 4; ++j) {
            half8 h;
#pragma unroll
            for (int r = 0; r < 8; ++r) h[r] = (_Float16)((&pv4[r].x)[j]);
            const int byte_off = (n8 * 1024 + c0 + j) * 16;
            *(half8*)((char*)Bs + bs_swz(byte_off)) = h;
        }
        __syncthreads();
        // ---- prefetch next chunk (overlaps with compute below) ----
        if (kt + 1 < 16) {
            const float* src = FVi + (size_t)((kt + 1) * 16 + n8 * 8) * 1024 + c0;
#pragma unroll
            for (int r = 0; r < 8; ++r) pv4[r] = *(const float4*)(src + (size_t)r * 1024);
            if (tid < 128) {
                const float* ap = Mf + (size_t)(bt * 64 + am) * 256 + (kt + 1) * 16 + akg * 8;
                pa0 = *(const float4*)(ap);
                pa1 = *(const float4*)(ap + 4);
            }
        }
        // ---- compute: 8 n-tiles x (hi,lo) MFMA ----
        const half8 ah = *(half8*)&AsHi[(l5 * 64 + wy * 32 + l31) * 8];
        const half8 al = *(half8*)&AsLo[(l5 * 64 + wy * 32 + l31) * 8];
#pragma unroll
        for (int nt = 0; nt < 8; ++nt) {
            const int byte_off = (l5 * 1024 + wx * 256 + nt * 32 + l31) * 16;
            const half8 b = *(const half8*)((const char*)Bs + bs_swz(byte_off));
            acc[nt] = __builtin_amdgcn_mfma_f32_32x32x16_f16(ah, b, acc[nt], 0, 0, 0);
            acc[nt] = __builtin_amdgcn_mfma_f32_32x32x16_f16(al, b, acc[nt], 0, 0, 0);
        }
    }

    // ---- softmax over d (rows span 4 wx waves) ----
    // lane holds: col = wx*256 + nt*32 + l31 ; row = wy*32 + (reg&3)+8*(reg>>2)+4*l5
    float st[16];
#pragma unroll
    for (int reg = 0; reg < 16; ++reg) {
        float v = acc[0][reg];
#pragma unroll
        for (int nt = 1; nt < 8; ++nt) v = fmaxf(v, acc[nt][reg]);
#pragma unroll
        for (int off = 1; off < 32; off <<= 1) v = fmaxf(v, __shfl_xor(v, off));
        st[reg] = v;
    }
    if (l31 == 0) {
#pragma unroll
        for (int reg = 0; reg < 16; ++reg) {
            const int row = wy * 32 + (reg & 3) + 8 * (reg >> 2) + 4 * l5;
            red1[row * 4 + wx] = st[reg];
        }
    }
    __syncthreads();
    float rmax[16];
#pragma unroll
    for (int reg = 0; reg < 16; ++reg) {
        const int row = wy * 32 + (reg & 3) + 8 * (reg >> 2) + 4 * l5;
        const float4 m4 = *(const float4*)&red1[row * 4];
        rmax[reg] = fmaxf(fmaxf(m4.x, m4.y), fmaxf(m4.z, m4.w));
    }
#pragma unroll
    for (int reg = 0; reg < 16; ++reg) {
        float s = 0.0f;
#pragma unroll
        for (int nt = 0; nt < 8; ++nt) {
            const float p = __expf(acc[nt][reg] - rmax[reg]);
            acc[nt][reg] = p;
            s += p;
        }
#pragma unroll
        for (int off = 1; off < 32; off <<= 1) s += __shfl_xor(s, off);
        st[reg] = s;
    }
    if (l31 == 0) {
#pragma unroll
        for (int reg = 0; reg < 16; ++reg) {
            const int row = wy * 32 + (reg & 3) + 8 * (reg >> 2) + 4 * l5;
            red2[row * 4 + wx] = st[reg];
        }
    }
    __syncthreads();
    float inv[16];
#pragma unroll
    for (int reg = 0; reg < 16; ++reg) {
        const int row = wy * 32 + (reg & 3) + 8 * (reg >> 2) + 4 * l5;
        const float4 s4 = *(const float4*)&red2[row * 4];
        inv[reg] = 1.0f / (s4.x + s4.y + s4.z + s4.w);
    }

    // ---- write W, accumulate context ----
    float csum[8];
#pragma unroll
    for (int nt = 0; nt < 8; ++nt) csum[nt] = 0.0f;

    const int rowbase = bt * 64 + wy * 32;
#pragma unroll
    for (int nt = 0; nt < 8; ++nt) {
        const int col = wx * 256 + nt * 32 + l31;
#pragma unroll
        for (int reg = 0; reg < 16; ++reg) {
            const int row = (reg & 3) + 8 * (reg >> 2) + 4 * l5;
            const float wv = acc[nt][reg] * inv[reg];
            Wout[((size_t)(i * 256 + rowbase + row)) * 1024 + col] = wv;
            const float fv = FVi[(size_t)(rowbase + row) * 1024 + col];
            csum[nt] += wv * fv;
        }
    }
#pragma unroll
    for (int nt = 0; nt < 8; ++nt) {
        const float v = csum[nt] + __shfl_xor(csum[nt], 32);
        if (l5 == 0)
            atomicAdd(&ctx[(size_t)i * 1024 + wx * 256 + nt * 32 + l31], v);
    }
}

// ---------------------------------------------------------------------------
extern "C" void kernel_launch(void* const* d_in, const int* in_sizes, int n_in,
                              void* d_out, int out_size, void* d_ws, size_t ws_size,
                              hipStream_t stream)
{
    const float* FV    = (const float*)d_in[0];  // [256,256,1024]
    const float* state = (const float*)d_in[1];  // [256,1024]
    const float* Q     = (const float*)d_in[2];  // [1024,1024]
    const float* Km    = (const float*)d_in[3];  // [1024,256]

    float* out = (float*)d_out;
    float* ctx = out;                 // [256,1024]
    float* W   = out + 256 * 1024;    // [256,256,1024]

    char* ws = (char*)d_ws;
    float* A1 = (float*)ws;               // [256,1024] fp32, 1 MB
    float* Mf = (float*)(ws + (1 << 20)); // [256,256]  fp32, 256 KB

    // split-K accumulators + ctx atomics -> zero them
    (void)hipMemsetAsync(ws, 0, (1 << 20) + (1 << 18), stream);
    (void)hipMemsetAsync(ctx, 0, 256 * 1024 * sizeof(float), stream);

    // A1 = state @ Q^T   (B stored [N,K]: Q[s,t], contract t), split-K x8
    gemm_splitk<true><<<dim3(16, 4, 8), 256, 0, stream>>>(
        state, Q, A1, 1024, 1024, 128);

    // M = A1 @ K  (B stored [K,N]), split-K x16
    gemm_splitk<false><<<dim3(4, 4, 16), 256, 0, stream>>>(
        A1, Km, Mf, 1024, 256, 64);

    // fused logits -> softmax -> W + ctx (R9 structure, session best)
    fused_attn<<<dim3(1024), 512, 0, stream>>>(FV, Mf, ctx, W);
}